// Round 1
// baseline (965.990 us; speedup 1.0000x reference)
//
#include <hip/hip_runtime.h>
#include <hip/hip_bf16.h>

#define N_NODES   50000
#define N_EDGES   500000
#define FDIM      128
#define N_CLASSES 32
#define N_GRAPHS  64

// ---------------------------------------------------------------------------
// Preprocessing: degree count, rsqrt, prefix scan, CSR fill
// ---------------------------------------------------------------------------

__global__ void deg_kernel(const int* __restrict__ dst, int* __restrict__ deg, int E) {
    int e = blockIdx.x * blockDim.x + threadIdx.x;
    if (e < E) atomicAdd(&deg[dst[e]], 1);
}

__global__ void dis_kernel(const int* __restrict__ deg, float* __restrict__ dis, int n) {
    int v = blockIdx.x * blockDim.x + threadIdx.x;
    if (v < n) dis[v] = rsqrtf((float)deg[v] + 1.0f);
}

__global__ void scan_partial(const int* __restrict__ deg, int* __restrict__ part, int n) {
    __shared__ int s[512];
    int t = threadIdx.x;
    int i = blockIdx.x * 512 + t;
    s[t] = (i < n) ? deg[i] : 0;
    __syncthreads();
    for (int o = 256; o > 0; o >>= 1) {
        if (t < o) s[t] += s[t + o];
        __syncthreads();
    }
    if (t == 0) part[blockIdx.x] = s[0];
}

__global__ void scan_offsets(int* part, int nb) {
    if (blockIdx.x == 0 && threadIdx.x == 0) {
        int acc = 0;
        for (int i = 0; i < nb; i++) { int v = part[i]; part[i] = acc; acc += v; }
    }
}

__global__ void scan_final(const int* __restrict__ deg, const int* __restrict__ part,
                           int* __restrict__ rowptr, int n) {
    __shared__ int s[512];
    int t = threadIdx.x;
    int i = blockIdx.x * 512 + t;
    int v = (i < n) ? deg[i] : 0;
    s[t] = v;
    __syncthreads();
    for (int o = 1; o < 512; o <<= 1) {
        int x = (t >= o) ? s[t - o] : 0;
        __syncthreads();
        s[t] += x;
        __syncthreads();
    }
    if (i < n) rowptr[i] = part[blockIdx.x] + s[t] - v;   // exclusive
}

__global__ void fill_csr(const int* __restrict__ src, const int* __restrict__ dst,
                         const int* __restrict__ rowptr, int* __restrict__ fill,
                         const float* __restrict__ dis,
                         int* __restrict__ csr_src, float* __restrict__ csr_w, int E) {
    int e = blockIdx.x * blockDim.x + threadIdx.x;
    if (e >= E) return;
    int d = dst[e], s = src[e];
    int pos = rowptr[d] + atomicAdd(&fill[d], 1);
    csr_src[pos] = s;
    csr_w[pos] = dis[s] * dis[d];
}

// ---------------------------------------------------------------------------
// GEMM: H[n][128] = X[n][128] @ W[128][128]
// 128x128 tile, 256 threads, 8x8 micro-tile, K chunks of 32
// ---------------------------------------------------------------------------

__global__ __launch_bounds__(256) void gemm128(const float* __restrict__ X,
                                               const float* __restrict__ W,
                                               float* __restrict__ H, int n) {
    __shared__ __align__(16) float xs[32][132];  // xs[k][row]  (transposed tile)
    __shared__ __align__(16) float ws[32][132];  // ws[k][col]
    int t = threadIdx.x;
    int i = t & 15;      // row micro index
    int j = t >> 4;      // col micro index
    int rowBase = blockIdx.x * 128;

    float acc[8][8];
#pragma unroll
    for (int r = 0; r < 8; r++)
#pragma unroll
        for (int c = 0; c < 8; c++) acc[r][c] = 0.f;

    for (int k0 = 0; k0 < 128; k0 += 32) {
        __syncthreads();
        // stage X transposed: kq = k-quad (0..7), r0 = row (0..31), 4 passes
        {
            int kq = t & 7, r0 = t >> 3;
#pragma unroll
            for (int p = 0; p < 4; p++) {
                int r = r0 + 32 * p;
                int grow = rowBase + r;
                float4 v = make_float4(0.f, 0.f, 0.f, 0.f);
                if (grow < n) v = *(const float4*)(X + (size_t)grow * FDIM + k0 + kq * 4);
                xs[kq * 4 + 0][r] = v.x;
                xs[kq * 4 + 1][r] = v.y;
                xs[kq * 4 + 2][r] = v.z;
                xs[kq * 4 + 3][r] = v.w;
            }
        }
        // stage W natural layout
        {
            int c4 = t & 31, kr = t >> 5;
#pragma unroll
            for (int p = 0; p < 4; p++) {
                int k = kr + 8 * p;
                float4 v = *(const float4*)(W + (size_t)(k0 + k) * FDIM + c4 * 4);
                *(float4*)&ws[k][c4 * 4] = v;
            }
        }
        __syncthreads();
#pragma unroll 8
        for (int k = 0; k < 32; k++) {
            float4 a0 = *(const float4*)&xs[k][i * 4];
            float4 a1 = *(const float4*)&xs[k][i * 4 + 64];
            float4 b0 = *(const float4*)&ws[k][j * 4];
            float4 b1 = *(const float4*)&ws[k][j * 4 + 64];
            float ar[8] = {a0.x, a0.y, a0.z, a0.w, a1.x, a1.y, a1.z, a1.w};
            float br[8] = {b0.x, b0.y, b0.z, b0.w, b1.x, b1.y, b1.z, b1.w};
#pragma unroll
            for (int r = 0; r < 8; r++)
#pragma unroll
                for (int c = 0; c < 8; c++) acc[r][c] = fmaf(ar[r], br[c], acc[r][c]);
        }
    }

#pragma unroll
    for (int rr = 0; rr < 8; rr++) {
        int r = (rr < 4) ? (i * 4 + rr) : (64 + i * 4 + (rr - 4));
        int grow = rowBase + r;
        if (grow < n) {
            float4 o0 = {acc[rr][0], acc[rr][1], acc[rr][2], acc[rr][3]};
            float4 o1 = {acc[rr][4], acc[rr][5], acc[rr][6], acc[rr][7]};
            *(float4*)(H + (size_t)grow * FDIM + j * 4) = o0;
            *(float4*)(H + (size_t)grow * FDIM + j * 4 + 64) = o1;
        }
    }
}

// ---------------------------------------------------------------------------
// Aggregate: OUT[v] = sum_e w_e * H[src_e] + (1/deg) * H[v] + b, optional ReLU
// One wave (64 lanes) per node, 2 floats per lane.
// ---------------------------------------------------------------------------

__global__ __launch_bounds__(256) void agg_kernel(const float* __restrict__ H,
                                                  float* __restrict__ OUT,
                                                  const int* __restrict__ rowptr,
                                                  const int* __restrict__ degi,
                                                  const int* __restrict__ csr_src,
                                                  const float* __restrict__ csr_w,
                                                  const float* __restrict__ dis,
                                                  const float* __restrict__ bias,
                                                  int n, int relu) {
    int wid = (blockIdx.x * blockDim.x + threadIdx.x) >> 6;
    int lane = threadIdx.x & 63;
    if (wid >= n) return;
    int v = wid;
    int start = rowptr[v];
    int cnt = degi[v];
    float ax = 0.f, ay = 0.f;
    for (int e = 0; e < cnt; e++) {
        int s = csr_src[start + e];
        float w = csr_w[start + e];
        float2 m = *(const float2*)(H + (size_t)s * FDIM + lane * 2);
        ax = fmaf(w, m.x, ax);
        ay = fmaf(w, m.y, ay);
    }
    float dv = dis[v];
    float ns = dv * dv;
    float2 hv = *(const float2*)(H + (size_t)v * FDIM + lane * 2);
    float2 bb = *(const float2*)(bias + lane * 2);
    float ox = ax + ns * hv.x + bb.x;
    float oy = ay + ns * hv.y + bb.y;
    if (relu) { ox = fmaxf(ox, 0.f); oy = fmaxf(oy, 0.f); }
    *(float2*)(OUT + (size_t)v * FDIM + lane * 2) = make_float2(ox, oy);
}

// ---------------------------------------------------------------------------
// Pooling + final linear
// ---------------------------------------------------------------------------

__global__ __launch_bounds__(256) void pool_kernel(const float* __restrict__ H,
                                                   const int* __restrict__ batch,
                                                   float* __restrict__ psum,
                                                   float* __restrict__ pcnt, int n) {
    int wid = (blockIdx.x * blockDim.x + threadIdx.x) >> 6;
    int lane = threadIdx.x & 63;
    if (wid >= n) return;
    int g = batch[wid];
    float2 h = *(const float2*)(H + (size_t)wid * FDIM + lane * 2);
    atomicAdd(&psum[g * FDIM + lane * 2 + 0], h.x);
    atomicAdd(&psum[g * FDIM + lane * 2 + 1], h.y);
    if (lane == 0) atomicAdd(&pcnt[g], 1.0f);
}

__global__ void final_lin(const float* __restrict__ psum, const float* __restrict__ pcnt,
                          const float* __restrict__ Wl, const float* __restrict__ bl,
                          float* __restrict__ out) {
    int t = blockIdx.x * blockDim.x + threadIdx.x;
    if (t >= N_GRAPHS * N_CLASSES) return;
    int g = t >> 5, c = t & 31;
    float inv = 1.0f / fmaxf(pcnt[g], 1.0f);
    float s = 0.f;
    for (int k = 0; k < FDIM; k++) s = fmaf(psum[g * FDIM + k], Wl[k * N_CLASSES + c], s);
    out[t] = s * inv + bl[c];
}

// ---------------------------------------------------------------------------

static inline size_t align256(size_t x) { return (x + 255) & ~(size_t)255; }

extern "C" void kernel_launch(void* const* d_in, const int* in_sizes, int n_in,
                              void* d_out, int out_size, void* d_ws, size_t ws_size,
                              hipStream_t stream) {
    const float* x     = (const float*)d_in[0];
    const int*   ei    = (const int*)d_in[1];
    const int*   batch = (const int*)d_in[2];
    const float* Wls[5] = {(const float*)d_in[3], (const float*)d_in[5], (const float*)d_in[7],
                           (const float*)d_in[9], (const float*)d_in[11]};
    const float* bls[5] = {(const float*)d_in[4], (const float*)d_in[6], (const float*)d_in[8],
                           (const float*)d_in[10], (const float*)d_in[12]};
    const float* W_lin = (const float*)d_in[13];
    const float* b_lin = (const float*)d_in[14];
    float* out = (float*)d_out;

    const int N = N_NODES, E = N_EDGES;
    const int* src = ei;
    const int* dst = ei + E;

    // workspace layout
    char* p = (char*)d_ws;
    size_t off = 0;
    float* hA = (float*)(p + off); off = align256(off + (size_t)N * FDIM * 4);
    float* hB = (float*)(p + off); off = align256(off + (size_t)N * FDIM * 4);
    int*   deg = (int*)(p + off); off = align256(off + (size_t)N * 4);
    float* dis = (float*)(p + off); off = align256(off + (size_t)N * 4);
    int*   rowptr = (int*)(p + off); off = align256(off + (size_t)N * 4);
    int*   fill = (int*)(p + off); off = align256(off + (size_t)N * 4);
    int*   part = (int*)(p + off); off = align256(off + 512);
    int*   csr_src = (int*)(p + off); off = align256(off + (size_t)E * 4);
    float* csr_w = (float*)(p + off); off = align256(off + (size_t)E * 4);
    float* psum = (float*)(p + off); off = align256(off + (size_t)N_GRAPHS * FDIM * 4);
    float* pcnt = (float*)(p + off); off = align256(off + (size_t)N_GRAPHS * 4);
    (void)ws_size; (void)n_in; (void)in_sizes; (void)out_size;

    // zero accumulators
    hipMemsetAsync(deg, 0, (size_t)N * 4, stream);
    hipMemsetAsync(fill, 0, (size_t)N * 4, stream);
    hipMemsetAsync(psum, 0, (size_t)N_GRAPHS * FDIM * 4, stream);
    hipMemsetAsync(pcnt, 0, (size_t)N_GRAPHS * 4, stream);

    // preprocessing
    deg_kernel<<<(E + 255) / 256, 256, 0, stream>>>(dst, deg, E);
    dis_kernel<<<(N + 255) / 256, 256, 0, stream>>>(deg, dis, N);
    int nChunks = (N + 511) / 512;  // 98
    scan_partial<<<nChunks, 512, 0, stream>>>(deg, part, N);
    scan_offsets<<<1, 64, 0, stream>>>(part, nChunks);
    scan_final<<<nChunks, 512, 0, stream>>>(deg, part, rowptr, N);
    fill_csr<<<(E + 255) / 256, 256, 0, stream>>>(src, dst, rowptr, fill, dis,
                                                  csr_src, csr_w, E);

    // 5 GCN layers, ping-pong hA/hB
    int gemmBlocks = (N + 127) / 128;  // 391
    int aggBlocks = (N * 64 + 255) / 256;  // 12500
    const float* cur = x;
    for (int l = 0; l < 5; l++) {
        gemm128<<<gemmBlocks, 256, 0, stream>>>(cur, Wls[l], hA, N);
        int relu = (l < 4) ? 1 : 0;
        agg_kernel<<<aggBlocks, 256, 0, stream>>>(hA, hB, rowptr, deg, csr_src, csr_w,
                                                  dis, bls[l], N, relu);
        cur = hB;
    }

    // pooling + classifier
    pool_kernel<<<aggBlocks, 256, 0, stream>>>(hB, batch, psum, pcnt, N);
    final_lin<<<(N_GRAPHS * N_CLASSES + 255) / 256, 256, 0, stream>>>(psum, pcnt, W_lin,
                                                                      b_lin, out);
}

// Round 2
// 584.974 us; speedup vs baseline: 1.6513x; 1.6513x over previous
//
#include <hip/hip_runtime.h>
#include <hip/hip_bf16.h>

#define N_NODES   50000
#define N_EDGES   500000
#define FDIM      128
#define N_CLASSES 32
#define N_GRAPHS  64

// ---------------------------------------------------------------------------
// Preprocessing: degree count, rsqrt, prefix scan, CSR fill
// ---------------------------------------------------------------------------

__global__ void deg_kernel(const int* __restrict__ dst, int* __restrict__ deg, int E) {
    int e = blockIdx.x * blockDim.x + threadIdx.x;
    if (e < E) atomicAdd(&deg[dst[e]], 1);
}

__global__ void dis_kernel(const int* __restrict__ deg, float* __restrict__ dis, int n) {
    int v = blockIdx.x * blockDim.x + threadIdx.x;
    if (v < n) dis[v] = rsqrtf((float)deg[v] + 1.0f);
}

__global__ void scan_partial(const int* __restrict__ deg, int* __restrict__ part, int n) {
    __shared__ int s[512];
    int t = threadIdx.x;
    int i = blockIdx.x * 512 + t;
    s[t] = (i < n) ? deg[i] : 0;
    __syncthreads();
    for (int o = 256; o > 0; o >>= 1) {
        if (t < o) s[t] += s[t + o];
        __syncthreads();
    }
    if (t == 0) part[blockIdx.x] = s[0];
}

__global__ void scan_offsets(int* part, int nb) {
    if (blockIdx.x == 0 && threadIdx.x == 0) {
        int acc = 0;
        for (int i = 0; i < nb; i++) { int v = part[i]; part[i] = acc; acc += v; }
    }
}

__global__ void scan_final(const int* __restrict__ deg, const int* __restrict__ part,
                           int* __restrict__ rowptr, int n) {
    __shared__ int s[512];
    int t = threadIdx.x;
    int i = blockIdx.x * 512 + t;
    int v = (i < n) ? deg[i] : 0;
    s[t] = v;
    __syncthreads();
    for (int o = 1; o < 512; o <<= 1) {
        int x = (t >= o) ? s[t - o] : 0;
        __syncthreads();
        s[t] += x;
        __syncthreads();
    }
    if (i < n) rowptr[i] = part[blockIdx.x] + s[t] - v;   // exclusive
}

__global__ void fill_csr(const int* __restrict__ src, const int* __restrict__ dst,
                         const int* __restrict__ rowptr, int* __restrict__ fill,
                         const float* __restrict__ dis,
                         int* __restrict__ csr_src, float* __restrict__ csr_w, int E) {
    int e = blockIdx.x * blockDim.x + threadIdx.x;
    if (e >= E) return;
    int d = dst[e], s = src[e];
    int pos = rowptr[d] + atomicAdd(&fill[d], 1);
    csr_src[pos] = s;
    csr_w[pos] = dis[s] * dis[d];
}

// ---------------------------------------------------------------------------
// GEMM: H[n][128] = X[n][128] @ W[128][128]
// 128x128 tile, 256 threads, 8x8 micro-tile, K chunks of 32
// ---------------------------------------------------------------------------

__global__ __launch_bounds__(256) void gemm128(const float* __restrict__ X,
                                               const float* __restrict__ W,
                                               float* __restrict__ H, int n) {
    __shared__ __align__(16) float xs[32][132];  // xs[k][row]  (transposed tile)
    __shared__ __align__(16) float ws[32][132];  // ws[k][col]
    int t = threadIdx.x;
    int i = t & 15;      // row micro index
    int j = t >> 4;      // col micro index
    int rowBase = blockIdx.x * 128;

    float acc[8][8];
#pragma unroll
    for (int r = 0; r < 8; r++)
#pragma unroll
        for (int c = 0; c < 8; c++) acc[r][c] = 0.f;

    for (int k0 = 0; k0 < 128; k0 += 32) {
        __syncthreads();
        // stage X transposed: kq = k-quad (0..7), r0 = row (0..31), 4 passes
        {
            int kq = t & 7, r0 = t >> 3;
#pragma unroll
            for (int p = 0; p < 4; p++) {
                int r = r0 + 32 * p;
                int grow = rowBase + r;
                float4 v = make_float4(0.f, 0.f, 0.f, 0.f);
                if (grow < n) v = *(const float4*)(X + (size_t)grow * FDIM + k0 + kq * 4);
                xs[kq * 4 + 0][r] = v.x;
                xs[kq * 4 + 1][r] = v.y;
                xs[kq * 4 + 2][r] = v.z;
                xs[kq * 4 + 3][r] = v.w;
            }
        }
        // stage W natural layout
        {
            int c4 = t & 31, kr = t >> 5;
#pragma unroll
            for (int p = 0; p < 4; p++) {
                int k = kr + 8 * p;
                float4 v = *(const float4*)(W + (size_t)(k0 + k) * FDIM + c4 * 4);
                *(float4*)&ws[k][c4 * 4] = v;
            }
        }
        __syncthreads();
#pragma unroll 8
        for (int k = 0; k < 32; k++) {
            float4 a0 = *(const float4*)&xs[k][i * 4];
            float4 a1 = *(const float4*)&xs[k][i * 4 + 64];
            float4 b0 = *(const float4*)&ws[k][j * 4];
            float4 b1 = *(const float4*)&ws[k][j * 4 + 64];
            float ar[8] = {a0.x, a0.y, a0.z, a0.w, a1.x, a1.y, a1.z, a1.w};
            float br[8] = {b0.x, b0.y, b0.z, b0.w, b1.x, b1.y, b1.z, b1.w};
#pragma unroll
            for (int r = 0; r < 8; r++)
#pragma unroll
                for (int c = 0; c < 8; c++) acc[r][c] = fmaf(ar[r], br[c], acc[r][c]);
        }
    }

#pragma unroll
    for (int rr = 0; rr < 8; rr++) {
        int r = (rr < 4) ? (i * 4 + rr) : (64 + i * 4 + (rr - 4));
        int grow = rowBase + r;
        if (grow < n) {
            float4 o0 = {acc[rr][0], acc[rr][1], acc[rr][2], acc[rr][3]};
            float4 o1 = {acc[rr][4], acc[rr][5], acc[rr][6], acc[rr][7]};
            *(float4*)(H + (size_t)grow * FDIM + j * 4) = o0;
            *(float4*)(H + (size_t)grow * FDIM + j * 4 + 64) = o1;
        }
    }
}

// ---------------------------------------------------------------------------
// Aggregate: OUT[v] = sum_e w_e * H[src_e] + (1/deg) * H[v] + b, optional ReLU
// One wave (64 lanes) per node, 2 floats per lane.
// ---------------------------------------------------------------------------

__global__ __launch_bounds__(256) void agg_kernel(const float* __restrict__ H,
                                                  float* __restrict__ OUT,
                                                  const int* __restrict__ rowptr,
                                                  const int* __restrict__ degi,
                                                  const int* __restrict__ csr_src,
                                                  const float* __restrict__ csr_w,
                                                  const float* __restrict__ dis,
                                                  const float* __restrict__ bias,
                                                  int n, int relu) {
    int wid = (blockIdx.x * blockDim.x + threadIdx.x) >> 6;
    int lane = threadIdx.x & 63;
    if (wid >= n) return;
    int v = wid;
    int start = rowptr[v];
    int cnt = degi[v];
    float ax = 0.f, ay = 0.f;
    for (int e = 0; e < cnt; e++) {
        int s = csr_src[start + e];
        float w = csr_w[start + e];
        float2 m = *(const float2*)(H + (size_t)s * FDIM + lane * 2);
        ax = fmaf(w, m.x, ax);
        ay = fmaf(w, m.y, ay);
    }
    float dv = dis[v];
    float ns = dv * dv;
    float2 hv = *(const float2*)(H + (size_t)v * FDIM + lane * 2);
    float2 bb = *(const float2*)(bias + lane * 2);
    float ox = ax + ns * hv.x + bb.x;
    float oy = ay + ns * hv.y + bb.y;
    if (relu) { ox = fmaxf(ox, 0.f); oy = fmaxf(oy, 0.f); }
    *(float2*)(OUT + (size_t)v * FDIM + lane * 2) = make_float2(ox, oy);
}

// ---------------------------------------------------------------------------
// Pooling: batch[] is SORTED. Each 128-thread block owns a contiguous node
// chunk; thread t owns feature t; flush one atomic per graph-boundary.
// ---------------------------------------------------------------------------

#define POOL_BLOCKS 1024

__global__ __launch_bounds__(128) void pool_kernel(const float* __restrict__ H,
                                                   const int* __restrict__ batch,
                                                   float* __restrict__ psum,
                                                   float* __restrict__ pcnt, int n) {
    int t = threadIdx.x;  // feature index 0..127
    int chunk = (n + POOL_BLOCKS - 1) / POOL_BLOCKS;
    int lo = blockIdx.x * chunk;
    int hi = lo + chunk; if (hi > n) hi = n;
    if (lo >= hi) return;

    float acc = 0.f;
    int cnt = 0;
    int curg = batch[lo];
    // one-deep software pipeline on the H row
    float hv = H[(size_t)lo * FDIM + t];
    int g = curg;
    for (int v = lo; v < hi; v++) {
        float hcur = hv;
        int gcur = g;
        if (v + 1 < hi) {
            hv = H[(size_t)(v + 1) * FDIM + t];
            g = batch[v + 1];
        }
        if (gcur != curg) {
            atomicAdd(&psum[curg * FDIM + t], acc);
            if (t == 0) atomicAdd(&pcnt[curg], (float)cnt);
            acc = 0.f; cnt = 0; curg = gcur;
        }
        acc += hcur;
        cnt++;
    }
    atomicAdd(&psum[curg * FDIM + t], acc);
    if (t == 0) atomicAdd(&pcnt[curg], (float)cnt);
}

__global__ void final_lin(const float* __restrict__ psum, const float* __restrict__ pcnt,
                          const float* __restrict__ Wl, const float* __restrict__ bl,
                          float* __restrict__ out) {
    int t = blockIdx.x * blockDim.x + threadIdx.x;
    if (t >= N_GRAPHS * N_CLASSES) return;
    int g = t >> 5, c = t & 31;
    float inv = 1.0f / fmaxf(pcnt[g], 1.0f);
    float s = 0.f;
    for (int k = 0; k < FDIM; k++) s = fmaf(psum[g * FDIM + k], Wl[k * N_CLASSES + c], s);
    out[t] = s * inv + bl[c];
}

// ---------------------------------------------------------------------------

static inline size_t align256(size_t x) { return (x + 255) & ~(size_t)255; }

extern "C" void kernel_launch(void* const* d_in, const int* in_sizes, int n_in,
                              void* d_out, int out_size, void* d_ws, size_t ws_size,
                              hipStream_t stream) {
    const float* x     = (const float*)d_in[0];
    const int*   ei    = (const int*)d_in[1];
    const int*   batch = (const int*)d_in[2];
    const float* Wls[5] = {(const float*)d_in[3], (const float*)d_in[5], (const float*)d_in[7],
                           (const float*)d_in[9], (const float*)d_in[11]};
    const float* bls[5] = {(const float*)d_in[4], (const float*)d_in[6], (const float*)d_in[8],
                           (const float*)d_in[10], (const float*)d_in[12]};
    const float* W_lin = (const float*)d_in[13];
    const float* b_lin = (const float*)d_in[14];
    float* out = (float*)d_out;

    const int N = N_NODES, E = N_EDGES;
    const int* src = ei;
    const int* dst = ei + E;

    // workspace layout
    char* p = (char*)d_ws;
    size_t off = 0;
    float* hA = (float*)(p + off); off = align256(off + (size_t)N * FDIM * 4);
    float* hB = (float*)(p + off); off = align256(off + (size_t)N * FDIM * 4);
    int*   deg = (int*)(p + off); off = align256(off + (size_t)N * 4);
    float* dis = (float*)(p + off); off = align256(off + (size_t)N * 4);
    int*   rowptr = (int*)(p + off); off = align256(off + (size_t)N * 4);
    int*   fill = (int*)(p + off); off = align256(off + (size_t)N * 4);
    int*   part = (int*)(p + off); off = align256(off + 512);
    int*   csr_src = (int*)(p + off); off = align256(off + (size_t)E * 4);
    float* csr_w = (float*)(p + off); off = align256(off + (size_t)E * 4);
    float* psum = (float*)(p + off); off = align256(off + (size_t)N_GRAPHS * FDIM * 4);
    float* pcnt = (float*)(p + off); off = align256(off + (size_t)N_GRAPHS * 4);
    (void)ws_size; (void)n_in; (void)in_sizes; (void)out_size;

    // zero accumulators
    hipMemsetAsync(deg, 0, (size_t)N * 4, stream);
    hipMemsetAsync(fill, 0, (size_t)N * 4, stream);
    hipMemsetAsync(psum, 0, (size_t)N_GRAPHS * FDIM * 4, stream);
    hipMemsetAsync(pcnt, 0, (size_t)N_GRAPHS * 4, stream);

    // preprocessing
    deg_kernel<<<(E + 255) / 256, 256, 0, stream>>>(dst, deg, E);
    dis_kernel<<<(N + 255) / 256, 256, 0, stream>>>(deg, dis, N);
    int nChunks = (N + 511) / 512;  // 98
    scan_partial<<<nChunks, 512, 0, stream>>>(deg, part, N);
    scan_offsets<<<1, 64, 0, stream>>>(part, nChunks);
    scan_final<<<nChunks, 512, 0, stream>>>(deg, part, rowptr, N);
    fill_csr<<<(E + 255) / 256, 256, 0, stream>>>(src, dst, rowptr, fill, dis,
                                                  csr_src, csr_w, E);

    // 5 GCN layers, ping-pong hA/hB
    int gemmBlocks = (N + 127) / 128;  // 391
    int aggBlocks = (N * 64 + 255) / 256;  // 12500
    const float* cur = x;
    for (int l = 0; l < 5; l++) {
        gemm128<<<gemmBlocks, 256, 0, stream>>>(cur, Wls[l], hA, N);
        int relu = (l < 4) ? 1 : 0;
        agg_kernel<<<aggBlocks, 256, 0, stream>>>(hA, hB, rowptr, deg, csr_src, csr_w,
                                                  dis, bls[l], N, relu);
        cur = hB;
    }

    // pooling + classifier
    pool_kernel<<<POOL_BLOCKS, 128, 0, stream>>>(hB, batch, psum, pcnt, N);
    final_lin<<<(N_GRAPHS * N_CLASSES + 255) / 256, 256, 0, stream>>>(psum, pcnt, W_lin,
                                                                      b_lin, out);
}

// Round 4
// 479.943 us; speedup vs baseline: 2.0127x; 1.2188x over previous
//
#include <hip/hip_runtime.h>
#include <hip/hip_bf16.h>

#define N_NODES   50000
#define N_EDGES   500000
#define FDIM      128
#define N_CLASSES 32
#define N_GRAPHS  64

// ---------------------------------------------------------------------------
// Preprocessing: degree count, rsqrt, prefix scan, CSR fill
// ---------------------------------------------------------------------------

__global__ void deg_kernel(const int* __restrict__ dst, int* __restrict__ deg, int E) {
    int e = blockIdx.x * blockDim.x + threadIdx.x;
    if (e < E) atomicAdd(&deg[dst[e]], 1);
}

__global__ void dis_kernel(const int* __restrict__ deg, float* __restrict__ dis, int n) {
    int v = blockIdx.x * blockDim.x + threadIdx.x;
    if (v < n) dis[v] = rsqrtf((float)deg[v] + 1.0f);
}

__global__ void scan_partial(const int* __restrict__ deg, int* __restrict__ part, int n) {
    __shared__ int s[512];
    int t = threadIdx.x;
    int i = blockIdx.x * 512 + t;
    s[t] = (i < n) ? deg[i] : 0;
    __syncthreads();
    for (int o = 256; o > 0; o >>= 1) {
        if (t < o) s[t] += s[t + o];
        __syncthreads();
    }
    if (t == 0) part[blockIdx.x] = s[0];
}

__global__ void scan_offsets(int* part, int nb) {
    if (blockIdx.x == 0 && threadIdx.x == 0) {
        int acc = 0;
        for (int i = 0; i < nb; i++) { int v = part[i]; part[i] = acc; acc += v; }
    }
}

__global__ void scan_final(const int* __restrict__ deg, const int* __restrict__ part,
                           int* __restrict__ rowptr, int n) {
    __shared__ int s[512];
    int t = threadIdx.x;
    int i = blockIdx.x * 512 + t;
    int v = (i < n) ? deg[i] : 0;
    s[t] = v;
    __syncthreads();
    for (int o = 1; o < 512; o <<= 1) {
        int x = (t >= o) ? s[t - o] : 0;
        __syncthreads();
        s[t] += x;
        __syncthreads();
    }
    if (i < n) rowptr[i] = part[blockIdx.x] + s[t] - v;   // exclusive
}

__global__ void fill_csr(const int* __restrict__ src, const int* __restrict__ dst,
                         const int* __restrict__ rowptr, int* __restrict__ fill,
                         const float* __restrict__ dis,
                         int2* __restrict__ csr_sw, int E) {
    int e = blockIdx.x * blockDim.x + threadIdx.x;
    if (e >= E) return;
    int d = dst[e], s = src[e];
    int pos = rowptr[d] + atomicAdd(&fill[d], 1);
    float w = dis[s] * dis[d];
    csr_sw[pos] = make_int2(s, __float_as_int(w));
}

// ---------------------------------------------------------------------------
// GEMM: H[n][128] = X[n][128] @ W[128][128]
// 128x128 tile, 256 threads, 8x8 micro-tile, K chunks of 32
// ---------------------------------------------------------------------------

__global__ __launch_bounds__(256) void gemm128(const float* __restrict__ X,
                                               const float* __restrict__ W,
                                               float* __restrict__ H, int n) {
    __shared__ __align__(16) float xs[32][132];  // xs[k][row]  (transposed tile)
    __shared__ __align__(16) float ws[32][132];  // ws[k][col]
    int t = threadIdx.x;
    int i = t & 15;      // row micro index
    int j = t >> 4;      // col micro index
    int rowBase = blockIdx.x * 128;

    float acc[8][8];
#pragma unroll
    for (int r = 0; r < 8; r++)
#pragma unroll
        for (int c = 0; c < 8; c++) acc[r][c] = 0.f;

    for (int k0 = 0; k0 < 128; k0 += 32) {
        __syncthreads();
        // stage X transposed: kq = k-quad (0..7), r0 = row (0..31), 4 passes
        {
            int kq = t & 7, r0 = t >> 3;
#pragma unroll
            for (int p = 0; p < 4; p++) {
                int r = r0 + 32 * p;
                int grow = rowBase + r;
                float4 v = make_float4(0.f, 0.f, 0.f, 0.f);
                if (grow < n) v = *(const float4*)(X + (size_t)grow * FDIM + k0 + kq * 4);
                xs[kq * 4 + 0][r] = v.x;
                xs[kq * 4 + 1][r] = v.y;
                xs[kq * 4 + 2][r] = v.z;
                xs[kq * 4 + 3][r] = v.w;
            }
        }
        // stage W natural layout
        {
            int c4 = t & 31, kr = t >> 5;
#pragma unroll
            for (int p = 0; p < 4; p++) {
                int k = kr + 8 * p;
                float4 v = *(const float4*)(W + (size_t)(k0 + k) * FDIM + c4 * 4);
                *(float4*)&ws[k][c4 * 4] = v;
            }
        }
        __syncthreads();
#pragma unroll 8
        for (int k = 0; k < 32; k++) {
            float4 a0 = *(const float4*)&xs[k][i * 4];
            float4 a1 = *(const float4*)&xs[k][i * 4 + 64];
            float4 b0 = *(const float4*)&ws[k][j * 4];
            float4 b1 = *(const float4*)&ws[k][j * 4 + 64];
            float ar[8] = {a0.x, a0.y, a0.z, a0.w, a1.x, a1.y, a1.z, a1.w};
            float br[8] = {b0.x, b0.y, b0.z, b0.w, b1.x, b1.y, b1.z, b1.w};
#pragma unroll
            for (int r = 0; r < 8; r++)
#pragma unroll
                for (int c = 0; c < 8; c++) acc[r][c] = fmaf(ar[r], br[c], acc[r][c]);
        }
    }

#pragma unroll
    for (int rr = 0; rr < 8; rr++) {
        int r = (rr < 4) ? (i * 4 + rr) : (64 + i * 4 + (rr - 4));
        int grow = rowBase + r;
        if (grow < n) {
            float4 o0 = {acc[rr][0], acc[rr][1], acc[rr][2], acc[rr][3]};
            float4 o1 = {acc[rr][4], acc[rr][5], acc[rr][6], acc[rr][7]};
            *(float4*)(H + (size_t)grow * FDIM + j * 4) = o0;
            *(float4*)(H + (size_t)grow * FDIM + j * 4 + 64) = o1;
        }
    }
}

// ---------------------------------------------------------------------------
// Aggregate: OUT[v] = sum_e w_e * H[src_e] + (1/deg) * H[v] + b, optional ReLU
// One wave (64 lanes) per node, 2 floats per lane.
// 8/4/1-deep unroll keeps multiple gathers in flight (breaks the latency chain).
// ---------------------------------------------------------------------------

__global__ __launch_bounds__(256) void agg_kernel(const float* __restrict__ H,
                                                  float* __restrict__ OUT,
                                                  const int* __restrict__ rowptr,
                                                  const int* __restrict__ degi,
                                                  const int2* __restrict__ csr_sw,
                                                  const float* __restrict__ dis,
                                                  const float* __restrict__ bias,
                                                  int n, int relu) {
    int wid = (blockIdx.x * blockDim.x + threadIdx.x) >> 6;
    int lane = threadIdx.x & 63;
    if (wid >= n) return;
    int v = wid;
    const int2* sw = csr_sw + rowptr[v];
    int cnt = degi[v];
    float ax = 0.f, ay = 0.f;
    int e = 0;

    for (; e + 8 <= cnt; e += 8) {
        int2 p0 = sw[e + 0], p1 = sw[e + 1], p2 = sw[e + 2], p3 = sw[e + 3];
        int2 p4 = sw[e + 4], p5 = sw[e + 5], p6 = sw[e + 6], p7 = sw[e + 7];
        float2 m0 = *(const float2*)(H + (size_t)p0.x * FDIM + lane * 2);
        float2 m1 = *(const float2*)(H + (size_t)p1.x * FDIM + lane * 2);
        float2 m2 = *(const float2*)(H + (size_t)p2.x * FDIM + lane * 2);
        float2 m3 = *(const float2*)(H + (size_t)p3.x * FDIM + lane * 2);
        float2 m4 = *(const float2*)(H + (size_t)p4.x * FDIM + lane * 2);
        float2 m5 = *(const float2*)(H + (size_t)p5.x * FDIM + lane * 2);
        float2 m6 = *(const float2*)(H + (size_t)p6.x * FDIM + lane * 2);
        float2 m7 = *(const float2*)(H + (size_t)p7.x * FDIM + lane * 2);
        ax = fmaf(__int_as_float(p0.y), m0.x, ax); ay = fmaf(__int_as_float(p0.y), m0.y, ay);
        ax = fmaf(__int_as_float(p1.y), m1.x, ax); ay = fmaf(__int_as_float(p1.y), m1.y, ay);
        ax = fmaf(__int_as_float(p2.y), m2.x, ax); ay = fmaf(__int_as_float(p2.y), m2.y, ay);
        ax = fmaf(__int_as_float(p3.y), m3.x, ax); ay = fmaf(__int_as_float(p3.y), m3.y, ay);
        ax = fmaf(__int_as_float(p4.y), m4.x, ax); ay = fmaf(__int_as_float(p4.y), m4.y, ay);
        ax = fmaf(__int_as_float(p5.y), m5.x, ax); ay = fmaf(__int_as_float(p5.y), m5.y, ay);
        ax = fmaf(__int_as_float(p6.y), m6.x, ax); ay = fmaf(__int_as_float(p6.y), m6.y, ay);
        ax = fmaf(__int_as_float(p7.y), m7.x, ax); ay = fmaf(__int_as_float(p7.y), m7.y, ay);
    }
    for (; e + 4 <= cnt; e += 4) {
        int2 p0 = sw[e + 0], p1 = sw[e + 1], p2 = sw[e + 2], p3 = sw[e + 3];
        float2 m0 = *(const float2*)(H + (size_t)p0.x * FDIM + lane * 2);
        float2 m1 = *(const float2*)(H + (size_t)p1.x * FDIM + lane * 2);
        float2 m2 = *(const float2*)(H + (size_t)p2.x * FDIM + lane * 2);
        float2 m3 = *(const float2*)(H + (size_t)p3.x * FDIM + lane * 2);
        ax = fmaf(__int_as_float(p0.y), m0.x, ax); ay = fmaf(__int_as_float(p0.y), m0.y, ay);
        ax = fmaf(__int_as_float(p1.y), m1.x, ax); ay = fmaf(__int_as_float(p1.y), m1.y, ay);
        ax = fmaf(__int_as_float(p2.y), m2.x, ax); ay = fmaf(__int_as_float(p2.y), m2.y, ay);
        ax = fmaf(__int_as_float(p3.y), m3.x, ax); ay = fmaf(__int_as_float(p3.y), m3.y, ay);
    }
    for (; e < cnt; e++) {
        int2 p = sw[e];
        float2 m = *(const float2*)(H + (size_t)p.x * FDIM + lane * 2);
        ax = fmaf(__int_as_float(p.y), m.x, ax);
        ay = fmaf(__int_as_float(p.y), m.y, ay);
    }

    float dv = dis[v];
    float ns = dv * dv;
    float2 hv = *(const float2*)(H + (size_t)v * FDIM + lane * 2);
    float2 bb = *(const float2*)(bias + lane * 2);
    float ox = ax + ns * hv.x + bb.x;
    float oy = ay + ns * hv.y + bb.y;
    if (relu) { ox = fmaxf(ox, 0.f); oy = fmaxf(oy, 0.f); }
    *(float2*)(OUT + (size_t)v * FDIM + lane * 2) = make_float2(ox, oy);
}

// ---------------------------------------------------------------------------
// Pooling: batch[] is SORTED. Each 128-thread block owns a contiguous node
// chunk; thread t owns feature t; flush one atomic per graph-boundary.
// ---------------------------------------------------------------------------

#define POOL_BLOCKS 1024

__global__ __launch_bounds__(128) void pool_kernel(const float* __restrict__ H,
                                                   const int* __restrict__ batch,
                                                   float* __restrict__ psum,
                                                   float* __restrict__ pcnt, int n) {
    int t = threadIdx.x;  // feature index 0..127
    int chunk = (n + POOL_BLOCKS - 1) / POOL_BLOCKS;
    int lo = blockIdx.x * chunk;
    int hi = lo + chunk; if (hi > n) hi = n;
    if (lo >= hi) return;

    float acc = 0.f;
    int cnt = 0;
    int curg = batch[lo];
    float hv = H[(size_t)lo * FDIM + t];
    int g = curg;
    for (int v = lo; v < hi; v++) {
        float hcur = hv;
        int gcur = g;
        if (v + 1 < hi) {
            hv = H[(size_t)(v + 1) * FDIM + t];
            g = batch[v + 1];
        }
        if (gcur != curg) {
            atomicAdd(&psum[curg * FDIM + t], acc);
            if (t == 0) atomicAdd(&pcnt[curg], (float)cnt);
            acc = 0.f; cnt = 0; curg = gcur;
        }
        acc += hcur;
        cnt++;
    }
    atomicAdd(&psum[curg * FDIM + t], acc);
    if (t == 0) atomicAdd(&pcnt[curg], (float)cnt);
}

__global__ void final_lin(const float* __restrict__ psum, const float* __restrict__ pcnt,
                          const float* __restrict__ Wl, const float* __restrict__ bl,
                          float* __restrict__ out) {
    int t = blockIdx.x * blockDim.x + threadIdx.x;
    if (t >= N_GRAPHS * N_CLASSES) return;
    int g = t >> 5, c = t & 31;
    float inv = 1.0f / fmaxf(pcnt[g], 1.0f);
    float s = 0.f;
    for (int k = 0; k < FDIM; k++) s = fmaf(psum[g * FDIM + k], Wl[k * N_CLASSES + c], s);
    out[t] = s * inv + bl[c];
}

// ---------------------------------------------------------------------------

static inline size_t align256(size_t x) { return (x + 255) & ~(size_t)255; }

extern "C" void kernel_launch(void* const* d_in, const int* in_sizes, int n_in,
                              void* d_out, int out_size, void* d_ws, size_t ws_size,
                              hipStream_t stream) {
    const float* x     = (const float*)d_in[0];
    const int*   ei    = (const int*)d_in[1];
    const int*   batch = (const int*)d_in[2];
    const float* Wls[5] = {(const float*)d_in[3], (const float*)d_in[5], (const float*)d_in[7],
                           (const float*)d_in[9], (const float*)d_in[11]};
    const float* bls[5] = {(const float*)d_in[4], (const float*)d_in[6], (const float*)d_in[8],
                           (const float*)d_in[10], (const float*)d_in[12]};
    const float* W_lin = (const float*)d_in[13];
    const float* b_lin = (const float*)d_in[14];
    float* out = (float*)d_out;

    const int N = N_NODES, E = N_EDGES;
    const int* src = ei;
    const int* dst = ei + E;

    // workspace layout
    char* p = (char*)d_ws;
    size_t off = 0;
    float* hA = (float*)(p + off); off = align256(off + (size_t)N * FDIM * 4);
    float* hB = (float*)(p + off); off = align256(off + (size_t)N * FDIM * 4);
    int*   deg = (int*)(p + off); off = align256(off + (size_t)N * 4);
    float* dis = (float*)(p + off); off = align256(off + (size_t)N * 4);
    int*   rowptr = (int*)(p + off); off = align256(off + (size_t)N * 4);
    int*   fill = (int*)(p + off); off = align256(off + (size_t)N * 4);
    int*   part = (int*)(p + off); off = align256(off + 512);
    int2*  csr_sw = (int2*)(p + off); off = align256(off + (size_t)E * 8);
    float* psum = (float*)(p + off); off = align256(off + (size_t)N_GRAPHS * FDIM * 4);
    float* pcnt = (float*)(p + off); off = align256(off + (size_t)N_GRAPHS * 4);
    (void)ws_size; (void)n_in; (void)in_sizes; (void)out_size;

    // zero accumulators
    hipMemsetAsync(deg, 0, (size_t)N * 4, stream);
    hipMemsetAsync(fill, 0, (size_t)N * 4, stream);
    hipMemsetAsync(psum, 0, (size_t)N_GRAPHS * FDIM * 4, stream);
    hipMemsetAsync(pcnt, 0, (size_t)N_GRAPHS * 4, stream);

    // preprocessing
    deg_kernel<<<(E + 255) / 256, 256, 0, stream>>>(dst, deg, E);
    dis_kernel<<<(N + 255) / 256, 256, 0, stream>>>(deg, dis, N);
    int nChunks = (N + 511) / 512;  // 98
    scan_partial<<<nChunks, 512, 0, stream>>>(deg, part, N);
    scan_offsets<<<1, 64, 0, stream>>>(part, nChunks);
    scan_final<<<nChunks, 512, 0, stream>>>(deg, part, rowptr, N);
    fill_csr<<<(E + 255) / 256, 256, 0, stream>>>(src, dst, rowptr, fill, dis,
                                                  csr_sw, E);

    // 5 GCN layers, ping-pong hA/hB
    int gemmBlocks = (N + 127) / 128;  // 391
    int aggBlocks = (N * 64 + 255) / 256;  // 12500
    const float* cur = x;
    for (int l = 0; l < 5; l++) {
        gemm128<<<gemmBlocks, 256, 0, stream>>>(cur, Wls[l], hA, N);
        int relu = (l < 4) ? 1 : 0;
        agg_kernel<<<aggBlocks, 256, 0, stream>>>(hA, hB, rowptr, deg, csr_sw,
                                                  dis, bls[l], N, relu);
        cur = hB;
    }

    // pooling + classifier
    pool_kernel<<<POOL_BLOCKS, 128, 0, stream>>>(hB, batch, psum, pcnt, N);
    final_lin<<<(N_GRAPHS * N_CLASSES + 255) / 256, 256, 0, stream>>>(psum, pcnt, W_lin,
                                                                      b_lin, out);
}